// Round 1
// baseline (66.697 us; speedup 1.0000x reference)
//
#include <hip/hip_runtime.h>

#define NBATCH 2048
#define NROWS 8
#define NDIM 64
#define ROW_PITCH 68          // 272B rows: 16B-aligned, rows spread across banks
#define WPB 4                 // waves (=batches) per block
#define NBLOCKS (NBATCH / WPB)

// VALU-class lane permutes (DPP), compile-time control
template<int CTRL>
__device__ __forceinline__ float dpp_perm(float x) {
    const int xi = __float_as_int(x);
    return __int_as_float(__builtin_amdgcn_update_dpp(xi, xi, CTRL, 0xF, 0xF, true));
}
// Single-instruction LDS swizzle (no address VGPR, unlike ds_bpermute)
template<int PAT>
__device__ __forceinline__ float swz(float x) {
    return __int_as_float(__builtin_amdgcn_ds_swizzle(__float_as_int(x), PAT));
}

// One wave per batch; 4 batches per 256-thread block; wave-private LDS slices.
// C-matrix from LDS-staged inputs; Held-Karp DP in registers:
//   dp[mask] at reg q = mask>>6, lane = mask&63.
//   xor1 -> quad_perm[1,0,3,2]; xor2 -> quad_perm[2,3,0,1]; xor8 -> row_ror:8
//   (VALU pipe); xor4/xor16 -> ds_swizzle; xor32 -> __shfl_xor; bits 6,7 -> reg swap.
__global__ __launch_bounds__(256)
void assignment_fused(const float* __restrict__ y_true,
                      const float* __restrict__ y_pred,
                      float* __restrict__ out) {
    __shared__ __align__(16) float s_yt[WPB][NROWS * ROW_PITCH];
    __shared__ __align__(16) float s_yp[WPB][NROWS * ROW_PITCH];
    __shared__ float s_part[WPB];

    const int tid  = threadIdx.x;
    const int lane = tid & 63;
    const int w    = tid >> 6;
    const int b    = blockIdx.x * WPB + w;

    const float* tb = y_true + (size_t)b * (NROWS * NDIM);
    const float* pb = y_pred + (size_t)b * (NROWS * NDIM);
    float* yt = s_yt[w];
    float* yp = s_yp[w];

    // ---- Stage 512 floats per array into this wave's LDS slice, float4 coalesced ----
    #pragma unroll
    for (int k = 0; k < 2; ++k) {
        const int l   = 4 * lane + 256 * k;
        const int row = l >> 6;
        const int d   = l & 63;
        *(float4*)&yt[row * ROW_PITCH + d] = *(const float4*)(tb + l);
        *(float4*)&yp[row * ROW_PITCH + d] = *(const float4*)(pb + l);
    }
    // Wave-synchronous LDS RAW: slices are wave-private, so no block barrier —
    // just force completion + compiler ordering.
    asm volatile("s_waitcnt lgkmcnt(0)" ::: "memory");

    // ---- C[i][j] in lane 8i+j (unnormalized SSD; /64 folded into final scale) ----
    float myC;
    {
        const int i = lane >> 3;
        const int j = lane & 7;
        const float* ai = &yt[i * ROW_PITCH];
        const float* pj = &yp[j * ROW_PITCH];
        float a0 = 0.f, a1 = 0.f, a2 = 0.f, a3 = 0.f;
        #pragma unroll
        for (int d = 0; d < NDIM; d += 4) {
            float4 va = *(const float4*)(ai + d);
            float4 vp = *(const float4*)(pj + d);
            float d0 = va.x - vp.x, d1 = va.y - vp.y;
            float d2 = va.z - vp.z, d3 = va.w - vp.w;
            a0 = fmaf(d0, d0, a0); a1 = fmaf(d1, d1, a1);
            a2 = fmaf(d2, d2, a2); a3 = fmaf(d3, d3, a3);
        }
        myC = (a0 + a1) + (a2 + a3);
    }

    // ---- Register Held-Karp over 256 masks ----
    const float INF = 1e30f;
    float dp[4];
    dp[0] = (lane == 0) ? 0.f : INF;
    dp[1] = INF; dp[2] = INF; dp[3] = INF;
    const int pl = __popc(lane);

    #pragma unroll
    for (int lv = 1; lv <= 8; ++lv) {
        const int r8 = (lv - 1) * 8;
        float c[8];
        #pragma unroll
        for (int j = 0; j < 8; ++j)
            c[j] = __shfl(myC, r8 + j, 64);        // compile-time lane -> v_readlane

        float nd[4];
        #pragma unroll
        for (int q = 0; q < 4; ++q) {
            const float d0 = dp[q];
            float best = INF, v;
            v = dpp_perm<0xB1>(d0)     + c[0]; best = (lane & 1)  ? fminf(best, v) : best; // xor1
            v = dpp_perm<0x4E>(d0)     + c[1]; best = (lane & 2)  ? fminf(best, v) : best; // xor2
            v = swz<0x101F>(d0)        + c[2]; best = (lane & 4)  ? fminf(best, v) : best; // xor4
            v = dpp_perm<0x128>(d0)    + c[3]; best = (lane & 8)  ? fminf(best, v) : best; // xor8 = row_ror:8
            v = swz<0x401F>(d0)        + c[4]; best = (lane & 16) ? fminf(best, v) : best; // xor16
            v = __shfl_xor(d0, 32, 64) + c[5]; best = (lane & 32) ? fminf(best, v) : best; // xor32
            if (q & 1) best = fminf(best, dp[q ^ 1] + c[6]);   // bit6 of m == q&1 (compile-time)
            if (q & 2) best = fminf(best, dp[q ^ 2] + c[7]);   // bit7 of m == q>>1
            nd[q] = best;
        }
        #pragma unroll
        for (int q = 0; q < 4; ++q)
            dp[q] = ((pl + (q & 1) + (q >> 1)) == lv) ? nd[q] : dp[q];
    }

    // dp[255] = register 3, lane 63
    float r = __shfl(dp[3], 63, 64);
    if (lane == 0) s_part[w] = r;
    __syncthreads();
    if (tid == 0) {
        float v = (s_part[0] + s_part[1]) + (s_part[2] + s_part[3]);
        atomicAdd(out, v * (1.0f / (64.0f * 8.0f * 2048.0f)));  // 512 atomics total
    }
}

extern "C" void kernel_launch(void* const* d_in, const int* in_sizes, int n_in,
                              void* d_out, int out_size, void* d_ws, size_t ws_size,
                              hipStream_t stream) {
    const float* y_true = (const float*)d_in[0];
    const float* y_pred = (const float*)d_in[1];
    // memset is stream-ordered and graph-capturable; replayed before the kernel
    // on every iteration, so atomicAdd accumulation starts from 0 each run.
    hipMemsetAsync(d_out, 0, sizeof(float), stream);
    assignment_fused<<<NBLOCKS, 256, 0, stream>>>(y_true, y_pred, (float*)d_out);
}

// Round 2
// 66.059 us; speedup vs baseline: 1.0097x; 1.0097x over previous
//
#include <hip/hip_runtime.h>

#define NBATCH 2048
#define NROWS 8
#define NDIM 64
#define ROW_PITCH 68          // 272B rows: 16B-aligned, rows spread across banks
#define WPB 8                 // waves (=batches) per block -> 256 blocks, 1/CU
#define NBLOCKS (NBATCH / WPB)

// VALU-class lane permutes (DPP), compile-time control
template<int CTRL>
__device__ __forceinline__ float dpp_perm(float x) {
    const int xi = __float_as_int(x);
    return __int_as_float(__builtin_amdgcn_update_dpp(xi, xi, CTRL, 0xF, 0xF, true));
}
// Single-instruction LDS swizzle (no address VGPR, unlike ds_bpermute)
template<int PAT>
__device__ __forceinline__ float swz(float x) {
    return __int_as_float(__builtin_amdgcn_ds_swizzle(__float_as_int(x), PAT));
}

// xor16 via v_permlane16_swap_b32 (VALU pipe, gfx950): with src==dst==x,
// r[0] = [x0:15,x0:15,x32:47,x32:47], r[1] = [x16:31,x16:31,x48:63,x48:63]
// -> lane wants x[lane^16] = (lane&16) ? r[0] : r[1]
__device__ __forceinline__ float perm_xor16(float x, int lane) {
#if __has_builtin(__builtin_amdgcn_permlane16_swap)
    unsigned xi = (unsigned)__float_as_int(x);
    auto r = __builtin_amdgcn_permlane16_swap(xi, xi, false, false);
    return __int_as_float((int)((lane & 16) ? r[0] : r[1]));
#else
    return __shfl_xor(x, 16, 64);
#endif
}
// xor32 via v_permlane32_swap_b32: r[0] = [x0:31|x0:31], r[1] = [x32:63|x32:63]
// -> lane wants x[lane^32] = (lane&32) ? r[0] : r[1]
__device__ __forceinline__ float perm_xor32(float x, int lane) {
#if __has_builtin(__builtin_amdgcn_permlane32_swap)
    unsigned xi = (unsigned)__float_as_int(x);
    auto r = __builtin_amdgcn_permlane32_swap(xi, xi, false, false);
    return __int_as_float((int)((lane & 32) ? r[0] : r[1]));
#else
    return __shfl_xor(x, 32, 64);
#endif
}

// One wave per batch; 8 batches per 512-thread block; wave-private LDS slices.
// C-matrix from LDS-staged inputs; Held-Karp DP in registers:
//   dp[mask] at reg q = mask>>6, lane = mask&63.
//   xor1/xor2 -> DPP quad_perm; xor8 -> DPP row_ror:8; xor16/xor32 -> permlane
//   swaps (all VALU pipe); only xor4 stays on LDS (ds_swizzle); bits 6,7 -> reg swap.
__global__ __launch_bounds__(512)
void assignment_fused(const float* __restrict__ y_true,
                      const float* __restrict__ y_pred,
                      float* __restrict__ out) {
    __shared__ __align__(16) float s_yt[WPB][NROWS * ROW_PITCH];
    __shared__ __align__(16) float s_yp[WPB][NROWS * ROW_PITCH];
    __shared__ float s_part[WPB];

    const int tid  = threadIdx.x;
    const int lane = tid & 63;
    const int w    = tid >> 6;
    const int b    = blockIdx.x * WPB + w;

    const float* tb = y_true + (size_t)b * (NROWS * NDIM);
    const float* pb = y_pred + (size_t)b * (NROWS * NDIM);
    float* yt = s_yt[w];
    float* yp = s_yp[w];

    // ---- Stage 512 floats per array into this wave's LDS slice, float4 coalesced ----
    #pragma unroll
    for (int k = 0; k < 2; ++k) {
        const int l   = 4 * lane + 256 * k;
        const int row = l >> 6;
        const int d   = l & 63;
        *(float4*)&yt[row * ROW_PITCH + d] = *(const float4*)(tb + l);
        *(float4*)&yp[row * ROW_PITCH + d] = *(const float4*)(pb + l);
    }
    // Wave-synchronous LDS RAW: slices are wave-private, so no block barrier —
    // just force completion + compiler ordering.
    asm volatile("s_waitcnt lgkmcnt(0)" ::: "memory");

    // ---- C[i][j] in lane 8i+j (unnormalized SSD; /64 folded into final scale) ----
    float myC;
    {
        const int i = lane >> 3;
        const int j = lane & 7;
        const float* ai = &yt[i * ROW_PITCH];
        const float* pj = &yp[j * ROW_PITCH];
        float a0 = 0.f, a1 = 0.f, a2 = 0.f, a3 = 0.f;
        #pragma unroll
        for (int d = 0; d < NDIM; d += 4) {
            float4 va = *(const float4*)(ai + d);
            float4 vp = *(const float4*)(pj + d);
            float d0 = va.x - vp.x, d1 = va.y - vp.y;
            float d2 = va.z - vp.z, d3 = va.w - vp.w;
            a0 = fmaf(d0, d0, a0); a1 = fmaf(d1, d1, a1);
            a2 = fmaf(d2, d2, a2); a3 = fmaf(d3, d3, a3);
        }
        myC = (a0 + a1) + (a2 + a3);
    }

    // ---- Register Held-Karp over 256 masks ----
    const float INF = 1e30f;
    float dp[4];
    dp[0] = (lane == 0) ? 0.f : INF;
    dp[1] = INF; dp[2] = INF; dp[3] = INF;
    const int pl = __popc(lane);

    #pragma unroll
    for (int lv = 1; lv <= 8; ++lv) {
        const int r8 = (lv - 1) * 8;
        float c[8];
        #pragma unroll
        for (int j = 0; j < 8; ++j)
            c[j] = __shfl(myC, r8 + j, 64);        // compile-time lane -> v_readlane

        float nd[4];
        #pragma unroll
        for (int q = 0; q < 4; ++q) {
            const float d0 = dp[q];
            float best = INF, v;
            v = dpp_perm<0xB1>(d0)    + c[0]; best = (lane & 1)  ? fminf(best, v) : best; // xor1
            v = dpp_perm<0x4E>(d0)    + c[1]; best = (lane & 2)  ? fminf(best, v) : best; // xor2
            v = swz<0x101F>(d0)       + c[2]; best = (lane & 4)  ? fminf(best, v) : best; // xor4
            v = dpp_perm<0x128>(d0)   + c[3]; best = (lane & 8)  ? fminf(best, v) : best; // xor8 = row_ror:8
            v = perm_xor16(d0, lane)  + c[4]; best = (lane & 16) ? fminf(best, v) : best; // xor16 (VALU)
            v = perm_xor32(d0, lane)  + c[5]; best = (lane & 32) ? fminf(best, v) : best; // xor32 (VALU)
            if (q & 1) best = fminf(best, dp[q ^ 1] + c[6]);   // bit6 of m == q&1 (compile-time)
            if (q & 2) best = fminf(best, dp[q ^ 2] + c[7]);   // bit7 of m == q>>1
            nd[q] = best;
        }
        #pragma unroll
        for (int q = 0; q < 4; ++q)
            dp[q] = ((pl + (q & 1) + (q >> 1)) == lv) ? nd[q] : dp[q];
    }

    // dp[255] = register 3, lane 63
    float r = __shfl(dp[3], 63, 64);
    if (lane == 0) s_part[w] = r;
    __syncthreads();
    if (tid == 0) {
        float v = 0.f;
        #pragma unroll
        for (int k = 0; k < WPB; ++k) v += s_part[k];
        atomicAdd(out, v * (1.0f / (64.0f * 8.0f * 2048.0f)));  // 256 atomics total
    }
}

extern "C" void kernel_launch(void* const* d_in, const int* in_sizes, int n_in,
                              void* d_out, int out_size, void* d_ws, size_t ws_size,
                              hipStream_t stream) {
    const float* y_true = (const float*)d_in[0];
    const float* y_pred = (const float*)d_in[1];
    // 4-byte memset: stream-ordered + graph-capturable; zeroes the atomic target
    // each iteration (output buffer is poisoned by the harness between runs).
    hipMemsetAsync(d_out, 0, sizeof(float), stream);
    assignment_fused<<<NBLOCKS, 512, 0, stream>>>(y_true, y_pred, (float*)d_out);
}